// Round 2
// baseline (315.230 us; speedup 1.0000x reference)
//
#include <hip/hip_runtime.h>
#include <hip/hip_bf16.h>
#include <stdint.h>
#include <stddef.h>

// DecoderStepLayer: B=16, Lq=1, L=2048 (self: 2047 hist + dec row; cross: enc 2048),
// D=1024, H=16, DK=DV=64, DF=4096.
// Reordered single-token attention (no K/V materialization); see R0 notes.
// R1: occupancy fixes — k_scores K-split across waves (32 waves/CU),
// k_ctx/k_skgemm double-buffered LDS with 1 barrier/iter, bigger KS splits,
// scr in [b][h][l] layout for coalesced softmax.

#define DEV __device__ __forceinline__

typedef __attribute__((ext_vector_type(8))) short bf16x8;
typedef __attribute__((ext_vector_type(4))) float f32x4;

DEV unsigned short f2b(float f){
  union { __hip_bfloat16 h; unsigned short u; } cv;
  cv.h = __float2bfloat16(f);
  return cv.u;
}
DEV float b2f(unsigned short u){
  union { unsigned int i; float f; } cv;
  cv.i = ((unsigned int)u) << 16;
  return cv.f;
}
DEV f32x4 mfma16(bf16x8 a, bf16x8 b, f32x4 c){
  return __builtin_amdgcn_mfma_f32_16x16x32_bf16(a, b, c, 0, 0, 0);
}

// ---------------------------------------------------------------------------
// K1a: Qb[b,h,k] = bf16( scale * sum_d src[b,d] * wq[h,d,k] )   grid 256, blk 256
__global__ __launch_bounds__(256) void k_qproj(const float* __restrict__ src,
    const float* __restrict__ wq, unsigned short* __restrict__ Qb, float scale){
  int bh = blockIdx.x, b = bh >> 4, h = bh & 15;
  int t = threadIdx.x, k = t & 63, q = t >> 6;
  const float* s = src + (size_t)b*1024 + q*256;
  const float* w = wq + (size_t)h*65536 + (size_t)(q*256)*64 + k;
  float a0=0.f,a1=0.f,a2=0.f,a3=0.f;
  for(int d=0; d<256; d+=4){
    a0 += s[d]   * w[(size_t)d*64];
    a1 += s[d+1] * w[(size_t)(d+1)*64];
    a2 += s[d+2] * w[(size_t)(d+2)*64];
    a3 += s[d+3] * w[(size_t)(d+3)*64];
  }
  __shared__ float red[256];
  red[t] = a0+a1+a2+a3;
  __syncthreads();
  if(t < 64){
    float v = red[t] + red[t+64] + red[t+128] + red[t+192];
    Qb[(size_t)bh*64 + t] = f2b(v*scale);
  }
}

// K1b: qpb[b,h,d] = bf16( sum_k wk[h,d,k] * Q[b,h,k] )          grid 256, blk 256
__global__ __launch_bounds__(256) void k_qp(const unsigned short* __restrict__ Qb,
    const float* __restrict__ wk, unsigned short* __restrict__ qpb){
  int bh = blockIdx.x, h = bh & 15;
  __shared__ float Q[64];
  if(threadIdx.x < 64) Q[threadIdx.x] = b2f(Qb[(size_t)bh*64 + threadIdx.x]);
  __syncthreads();
  for(int i=0;i<4;++i){
    int d = threadIdx.x + i*256;
    const float* w = wk + ((size_t)h*1024 + d)*64;
    float acc = 0.f;
    #pragma unroll
    for(int k=0;k<64;k+=4){
      float4 wv = *(const float4*)(w + k);
      acc += wv.x*Q[k] + wv.y*Q[k+1] + wv.z*Q[k+2] + wv.w*Q[k+3];
    }
    qpb[(size_t)bh*1024 + d] = f2b(acc);
  }
}

// K2: scr[b,h,l] = sum_d histcat[b,l,d]*qp[b,h,d]
// grid (128,16), blk 256: block = 16 rows, 4 waves K-split d (256 each), LDS reduce.
__global__ __launch_bounds__(256) void k_scores(const float* __restrict__ kvsrc,
    const float* __restrict__ decrow, const unsigned short* __restrict__ qpb,
    float* __restrict__ scr, int lsrc){
  int b = blockIdx.y;
  int t = threadIdx.x, lane = t & 63, w = t >> 6;
  int l0 = blockIdx.x*16;
  int hi = lane >> 4, r = lane & 15;
  int row = l0 + r;
  const float* rp = (row < lsrc) ? kvsrc + ((size_t)b*lsrc + row)*1024
                                 : decrow + (size_t)b*1024;
  int d0 = w*256;
  const float* ap = rp + d0 + hi*8;
  const unsigned short* bp = qpb + ((size_t)b*16 + r)*1024 + d0 + hi*8;
  f32x4 acc = {0.f,0.f,0.f,0.f};
  #pragma unroll
  for(int kk=0; kk<256; kk+=32){
    float4 a0 = *(const float4*)(ap + kk);
    float4 a1 = *(const float4*)(ap + kk + 4);
    bf16x8 af;
    af[0]=(short)f2b(a0.x); af[1]=(short)f2b(a0.y);
    af[2]=(short)f2b(a0.z); af[3]=(short)f2b(a0.w);
    af[4]=(short)f2b(a1.x); af[5]=(short)f2b(a1.y);
    af[6]=(short)f2b(a1.z); af[7]=(short)f2b(a1.w);
    bf16x8 bf_ = *(const bf16x8*)(bp + kk);
    acc = mfma16(af, bf_, acc);
  }
  __shared__ float red[1024];
  *(f32x4*)&red[t*4] = acc;
  __syncthreads();
  if(w == 0){
    #pragma unroll
    for(int i=0;i<4;++i){
      float v = red[(0*64+lane)*4+i] + red[(1*64+lane)*4+i]
              + red[(2*64+lane)*4+i] + red[(3*64+lane)*4+i];
      // D element (lane,i) -> (l = l0 + hi*4 + i, h = r)
      scr[((size_t)b*16 + r)*2048 + l0 + hi*4 + i] = v;
    }
  }
}

// K3: softmax over l per (b,h); writes fp32 probs to d_out slice + bf16 to ws.
__global__ __launch_bounds__(256) void k_softmax(const float* __restrict__ scr,
    float* __restrict__ attn_out, unsigned short* __restrict__ pb){
  int b = blockIdx.x >> 4, h = blockIdx.x & 15;
  int t = threadIdx.x;
  __shared__ float red[256];
  const float* s = scr + ((size_t)b*16 + h)*2048;
  float v[8];
  float m = -1e30f;
  #pragma unroll
  for(int i=0;i<8;++i){ v[i] = s[t + i*256]; m = fmaxf(m, v[i]); }
  red[t] = m; __syncthreads();
  for(int off=128; off>0; off>>=1){ if(t<off) red[t]=fmaxf(red[t],red[t+off]); __syncthreads(); }
  m = red[0]; __syncthreads();
  float sum = 0.f;
  #pragma unroll
  for(int i=0;i<8;++i){ v[i] = __expf(v[i]-m); sum += v[i]; }
  red[t] = sum; __syncthreads();
  for(int off=128; off>0; off>>=1){ if(t<off) red[t]+=red[t+off]; __syncthreads(); }
  float inv = 1.f/red[0];
  size_t base = ((size_t)b*16 + h)*2048;
  #pragma unroll
  for(int i=0;i<8;++i){
    float p = v[i]*inv;
    attn_out[base + t + i*256] = p;
    pb[base + t + i*256] = f2b(p);
  }
}

// K4: ctx partials: part[b,ks,h,d] = sum_{l in slice} p[b,h,l]*histcat[b,l,d]
// grid (dt=16, ks=8, b=16) = 2048 blocks, blk 256. Double-buffered LDS transpose.
__global__ __launch_bounds__(256) void k_ctx(const float* __restrict__ kvsrc,
    const float* __restrict__ decrow, const unsigned short* __restrict__ pb,
    float* __restrict__ part, int lsrc){
  int dt = blockIdx.x, ks = blockIdx.y, b = blockIdx.z;
  int d0 = dt*64, l0 = ks*256;
  __shared__ unsigned short lt[2][64*40];   // [buf][d 64][l 32 + pad]
  int t = threadIdx.x, lane = t & 63, w = t >> 6;
  int l_loc = t >> 3, d_off = (t & 7)*8;
  const unsigned short* ap = pb + ((size_t)b*16 + (lane & 15))*2048 + (lane >> 4)*8;
  f32x4 acc = {0.f,0.f,0.f,0.f};
  float4 x0, x1;
  auto LD = [&](int c){
    int lrow = l0 + c*32 + l_loc;
    const float* rp = (lrow < lsrc) ? kvsrc + ((size_t)b*lsrc + lrow)*1024
                                    : decrow + (size_t)b*1024;
    x0 = *(const float4*)(rp + d0 + d_off);
    x1 = *(const float4*)(rp + d0 + d_off + 4);
  };
  auto ST = [&](int buf){
    unsigned short* p = &lt[buf][0];
    p[(d_off+0)*40 + l_loc] = f2b(x0.x);
    p[(d_off+1)*40 + l_loc] = f2b(x0.y);
    p[(d_off+2)*40 + l_loc] = f2b(x0.z);
    p[(d_off+3)*40 + l_loc] = f2b(x0.w);
    p[(d_off+4)*40 + l_loc] = f2b(x1.x);
    p[(d_off+5)*40 + l_loc] = f2b(x1.y);
    p[(d_off+6)*40 + l_loc] = f2b(x1.z);
    p[(d_off+7)*40 + l_loc] = f2b(x1.w);
  };
  LD(0); ST(0);
  for(int c=0; c<8; ++c){
    if(c < 7) LD(c+1);                     // issue next chunk's loads early
    __syncthreads();                       // lt[c&1] writes visible
    bf16x8 af = *(const bf16x8*)(ap + l0 + c*32);
    bf16x8 bv = *(const bf16x8*)&lt[c&1][(w*16 + (lane & 15))*40 + (lane >> 4)*8];
    acc = mfma16(af, bv, acc);
    if(c < 7) ST((c+1)&1);                 // overwrites buffer last read pre-barrier
  }
  int col = d0 + w*16 + (lane & 15);
  int hrow = (lane >> 4)*4;
  #pragma unroll
  for(int i=0;i<4;++i)
    part[ (((size_t)b*8 + ks)*16 + hrow + i)*1024 + col ] = acc[i];
}

// K4.5: ctx[b,h,d] = sum_ks(8) part                      grid 1024, blk 256
__global__ __launch_bounds__(256) void k_ctxred(const float* __restrict__ part,
    float* __restrict__ ctx){
  int i = blockIdx.x*256 + threadIdx.x;
  int b = i >> 14, hd = i & 16383;
  size_t base = (size_t)b*131072 + hd;
  float s = 0.f;
  #pragma unroll
  for(int k=0;k<8;++k) s += part[base + (size_t)k*16384];
  ctx[i] = s;
}

// K5a: ob[b, h*64+v] = bf16( sum_d ctx[b,h,d]*wv[h,d,v] )  grid 256, blk 256
__global__ __launch_bounds__(256) void k_ov(const float* __restrict__ ctx,
    const float* __restrict__ wv, unsigned short* __restrict__ ob){
  int b = blockIdx.x >> 4, h = blockIdx.x & 15;
  int t = threadIdx.x, v = t & 63, q = t >> 6;
  const float* c = ctx + ((size_t)b*16 + h)*1024 + q*256;
  const float* w = wv + (size_t)h*65536 + (size_t)(q*256)*64 + v;
  float a0=0.f,a1=0.f,a2=0.f,a3=0.f;
  for(int d=0; d<256; d+=4){
    a0 += c[d]   * w[(size_t)d*64];
    a1 += c[d+1] * w[(size_t)(d+1)*64];
    a2 += c[d+2] * w[(size_t)(d+2)*64];
    a3 += c[d+3] * w[(size_t)(d+3)*64];
  }
  __shared__ float red[256];
  red[t] = a0+a1+a2+a3;
  __syncthreads();
  if(t < 64){
    float o = red[t] + red[t+64] + red[t+128] + red[t+192];
    ob[(size_t)b*1024 + h*64 + t] = f2b(o);
  }
}

// Skinny GEMM: part[ks,b,n] = A[16,Kslice] @ W[Kslice,N]   (A bf16, W fp32->bf16)
// grid (N/64, KS), blk 256. Double-buffered LDS-transposed W tile (pitch 40).
__global__ __launch_bounds__(256) void k_skgemm(const float* __restrict__ W,
    const unsigned short* __restrict__ A, float* __restrict__ part,
    int N, int K, int KS){
  int nt = blockIdx.x, ks = blockIdx.y;
  int Ksl = K / KS, k0b = ks * Ksl, n0 = nt*64;
  int nc = Ksl >> 5;
  __shared__ unsigned short lt[2][64*40];
  int t = threadIdx.x, lane = t & 63, w = t >> 6;
  int k_loc = t >> 3, n_off = (t & 7)*8;
  const unsigned short* apb = A + (size_t)(lane & 15)*K + (lane >> 4)*8 + k0b;
  f32x4 acc = {0.f,0.f,0.f,0.f};
  float4 x0, x1;
  auto LD = [&](int c){
    const float* wp = W + (size_t)(k0b + c*32 + k_loc)*N + n0 + n_off;
    x0 = *(const float4*)wp;
    x1 = *(const float4*)(wp + 4);
  };
  auto ST = [&](int buf){
    unsigned short* p = &lt[buf][0];
    p[(n_off+0)*40 + k_loc] = f2b(x0.x);
    p[(n_off+1)*40 + k_loc] = f2b(x0.y);
    p[(n_off+2)*40 + k_loc] = f2b(x0.z);
    p[(n_off+3)*40 + k_loc] = f2b(x0.w);
    p[(n_off+4)*40 + k_loc] = f2b(x1.x);
    p[(n_off+5)*40 + k_loc] = f2b(x1.y);
    p[(n_off+6)*40 + k_loc] = f2b(x1.z);
    p[(n_off+7)*40 + k_loc] = f2b(x1.w);
  };
  LD(0); ST(0);
  for(int c=0; c<nc; ++c){
    if(c+1 < nc) LD(c+1);
    __syncthreads();
    bf16x8 af = *(const bf16x8*)(apb + c*32);
    bf16x8 bv = *(const bf16x8*)&lt[c&1][(w*16 + (lane & 15))*40 + (lane >> 4)*8];
    acc = mfma16(af, bv, acc);
    if(c+1 < nc) ST((c+1)&1);
  }
  int col = n0 + w*16 + (lane & 15);
  int r0 = (lane >> 4)*4;
  #pragma unroll
  for(int i=0;i<4;++i)
    part[ ((size_t)ks*16 + r0 + i)*(size_t)N + col ] = acc[i];
}

// LN( sum_ks parts + bias + resid ) * g + bb  -> xout (fp32) [+ bf16]  grid 16
__global__ __launch_bounds__(256) void k_lnres(const float* __restrict__ parts, int KS,
    const float* __restrict__ bias, const float* __restrict__ resid,
    const float* __restrict__ g, const float* __restrict__ bb,
    float* __restrict__ xout, unsigned short* __restrict__ xb16){
  int b = blockIdx.x, t = threadIdx.x;
  __shared__ float red[256];
  float vals[4];
  float lsum = 0.f;
  for(int i=0;i<4;++i){
    int d = t + i*256;
    float s = bias[d] + resid[(size_t)b*1024 + d];
    for(int k=0;k<KS;++k) s += parts[((size_t)k*16 + b)*1024 + d];
    vals[i] = s; lsum += s;
  }
  red[t] = lsum; __syncthreads();
  for(int off=128; off>0; off>>=1){ if(t<off) red[t]+=red[t+off]; __syncthreads(); }
  float mean = red[0]*(1.f/1024.f); __syncthreads();
  float vsum = 0.f;
  for(int i=0;i<4;++i){ float dd = vals[i]-mean; vsum += dd*dd; }
  red[t] = vsum; __syncthreads();
  for(int off=128; off>0; off>>=1){ if(t<off) red[t]+=red[t+off]; __syncthreads(); }
  float rstd = rsqrtf(red[0]*(1.f/1024.f) + 1e-5f);
  for(int i=0;i<4;++i){
    int d = t + i*256;
    float y = (vals[i]-mean)*rstd*g[d] + bb[d];
    if(xout) xout[(size_t)b*1024 + d] = y;
    if(xb16) xb16[(size_t)b*1024 + d] = f2b(y);
  }
}

// relu( sum_ks fparts + b1 ) -> h1 bf16 [16][4096]          grid 256
__global__ __launch_bounds__(256) void k_relu(const float* __restrict__ parts, int KS,
    const float* __restrict__ b1, unsigned short* __restrict__ h1){
  int i = blockIdx.x*256 + threadIdx.x;
  int f = i & 4095, b = i >> 12;
  float s = b1[f];
  for(int k=0;k<KS;++k) s += parts[((size_t)k*16 + b)*4096 + f];
  h1[i] = f2b(fmaxf(s, 0.f));
}

// ---------------------------------------------------------------------------
extern "C" void kernel_launch(void* const* d_in, const int* in_sizes, int n_in,
                              void* d_out, int out_size, void* d_ws, size_t ws_size,
                              hipStream_t stream){
  const float* dec    = (const float*)d_in[0];
  const float* hist   = (const float*)d_in[1];
  const float* enc    = (const float*)d_in[2];
  const float* wq_s   = (const float*)d_in[3];
  const float* wk_s   = (const float*)d_in[4];
  const float* wv_s   = (const float*)d_in[5];
  const float* wo_s   = (const float*)d_in[6];
  const float* bo_s   = (const float*)d_in[7];
  const float* ln1_g  = (const float*)d_in[8];
  const float* ln1_b  = (const float*)d_in[9];
  const float* wq_c   = (const float*)d_in[10];
  const float* wk_c   = (const float*)d_in[11];
  const float* wv_c   = (const float*)d_in[12];
  const float* wo_c   = (const float*)d_in[13];
  const float* bo_c   = (const float*)d_in[14];
  const float* ln2_g  = (const float*)d_in[15];
  const float* ln2_b  = (const float*)d_in[16];
  const float* ffn_w1 = (const float*)d_in[17];
  const float* ffn_b1 = (const float*)d_in[18];
  const float* ffn_w2 = (const float*)d_in[19];
  const float* ffn_b2 = (const float*)d_in[20];
  const float* ln3_g  = (const float*)d_in[21];
  const float* ln3_b  = (const float*)d_in[22];

  float* out      = (float*)d_out;              // [16][1024]
  float* slf_out  = out + 16384;                // [16][16][2048]
  float* enc_out  = out + 16384 + 524288;       // [16][16][2048]

  char* w = (char*)d_ws;
  float*          scr   = (float*)(w + 0x000000);           // 2 MB  [16][16][2048]
  unsigned short* pb    = (unsigned short*)(w + 0x200000);  // 1 MB  [16][16][2048]
  float*          part  = (float*)(w + 0x300000);           // 8 MB  [16][8][16][1024]
  float*          ctx   = (float*)(w + 0xB00000);           // 1 MB  [16][16][1024]
  unsigned short* qpb   = (unsigned short*)(w + 0xC00000);  // 512K  [16][16][1024]
  unsigned short* Qb    = (unsigned short*)(w + 0xC80000);  // 32K
  unsigned short* ob    = (unsigned short*)(w + 0xC90000);  // 32K   [16][1024]
  float*          x1    = (float*)(w + 0xCA0000);           // 64K
  float*          x2    = (float*)(w + 0xCB0000);           // 64K
  unsigned short* x2b   = (unsigned short*)(w + 0xCC0000);  // 32K
  unsigned short* h1b   = (unsigned short*)(w + 0xCD0000);  // 128K  [16][4096]
  float*          gpart = (float*)(w + 0xD00000);           // 1 MB  [16][16][1024]
  float*          fpart = (float*)(w + 0xE00000);           // 2 MB  [8][16][4096]
  float*          g2part= (float*)(w + 0x1000000);          // 2 MB  [32][16][1024]

  // ---- self attention ----
  k_qproj  <<<256, 256, 0, stream>>>(dec, wq_s, Qb, 0.125f);
  k_qp     <<<256, 256, 0, stream>>>(Qb, wk_s, qpb);
  k_scores <<<dim3(128,16), 256, 0, stream>>>(hist, dec, qpb, scr, 2047);
  k_softmax<<<256, 256, 0, stream>>>(scr, slf_out, pb);
  k_ctx    <<<dim3(16,8,16), 256, 0, stream>>>(hist, dec, pb, part, 2047);
  k_ctxred <<<1024, 256, 0, stream>>>(part, ctx);
  k_ov     <<<256, 256, 0, stream>>>(ctx, wv_s, ob);
  k_skgemm <<<dim3(16,16), 256, 0, stream>>>(wo_s, ob, gpart, 1024, 1024, 16);
  k_lnres  <<<16, 256, 0, stream>>>(gpart, 16, bo_s, dec, ln1_g, ln1_b, x1, (unsigned short*)nullptr);

  // ---- cross attention ----
  k_qproj  <<<256, 256, 0, stream>>>(x1, wq_c, Qb, 0.125f);
  k_qp     <<<256, 256, 0, stream>>>(Qb, wk_c, qpb);
  k_scores <<<dim3(128,16), 256, 0, stream>>>(enc, dec, qpb, scr, 2048);
  k_softmax<<<256, 256, 0, stream>>>(scr, enc_out, pb);
  k_ctx    <<<dim3(16,8,16), 256, 0, stream>>>(enc, dec, pb, part, 2048);
  k_ctxred <<<1024, 256, 0, stream>>>(part, ctx);
  k_ov     <<<256, 256, 0, stream>>>(ctx, wv_c, ob);
  k_skgemm <<<dim3(16,16), 256, 0, stream>>>(wo_c, ob, gpart, 1024, 1024, 16);
  k_lnres  <<<16, 256, 0, stream>>>(gpart, 16, bo_c, x1, ln2_g, ln2_b, x2, x2b);

  // ---- FFN + final LN ----
  k_skgemm <<<dim3(64,8), 256, 0, stream>>>(ffn_w1, x2b, fpart, 4096, 1024, 8);
  k_relu   <<<256, 256, 0, stream>>>(fpart, 8, ffn_b1, h1b);
  k_skgemm <<<dim3(16,32), 256, 0, stream>>>(ffn_w2, h1b, g2part, 1024, 4096, 32);
  k_lnres  <<<16, 256, 0, stream>>>(g2part, 32, ffn_b2, x2, ln3_g, ln3_b, out, (unsigned short*)nullptr);
}

// Round 4
// 268.337 us; speedup vs baseline: 1.1748x; 1.1748x over previous
//
#include <hip/hip_runtime.h>
#include <hip/hip_bf16.h>
#include <stdint.h>
#include <stddef.h>

// DecoderStepLayer: B=16, Lq=1, L=2048 (self: 2047 hist + dec row; cross: enc 2048),
// D=1024, H=16, DK=DV=64, DF=4096.
// R3: flash-fused attention — each hist/enc row read from HBM exactly ONCE.
// R3 fix: k_fin applies 1/SUM to the combined context (was missing -> absmax 6.3).

#define DEV __device__ __forceinline__

typedef __attribute__((ext_vector_type(8))) short bf16x8;
typedef __attribute__((ext_vector_type(4))) float f32x4;

DEV unsigned short f2b(float f){
  union { __hip_bfloat16 h; unsigned short u; } cv;
  cv.h = __float2bfloat16(f);
  return cv.u;
}
DEV f32x4 mfma16(bf16x8 a, bf16x8 b, f32x4 c){
  return __builtin_amdgcn_mfma_f32_16x16x32_bf16(a, b, c, 0, 0, 0);
}

// ---------------------------------------------------------------------------
// K1: qpb[b,h,d] = bf16( sum_k wk[h,d,k] * (0.125 * sum_d' src[b,d']*wq[h,d',k]) )
__global__ __launch_bounds__(256) void k_qp2(const float* __restrict__ src,
    const float* __restrict__ wq, const float* __restrict__ wk,
    unsigned short* __restrict__ qpb){
  int bh = blockIdx.x, b = bh >> 4, h = bh & 15;
  int t = threadIdx.x;
  __shared__ float red[256];
  __shared__ float Qs[64];
  {
    int k = t & 63, q = t >> 6;
    const float* s = src + (size_t)b*1024 + q*256;
    const float* w = wq + (size_t)h*65536 + (size_t)(q*256)*64 + k;
    float a0=0.f,a1=0.f,a2=0.f,a3=0.f;
    for(int d=0; d<256; d+=4){
      a0 += s[d]   * w[(size_t)d*64];
      a1 += s[d+1] * w[(size_t)(d+1)*64];
      a2 += s[d+2] * w[(size_t)(d+2)*64];
      a3 += s[d+3] * w[(size_t)(d+3)*64];
    }
    red[t] = a0+a1+a2+a3;
    __syncthreads();
    if(t < 64) Qs[t] = (red[t]+red[t+64]+red[t+128]+red[t+192])*0.125f;
    __syncthreads();
  }
  for(int i=0;i<4;++i){
    int d = t + i*256;
    const float* w = wk + ((size_t)h*1024 + d)*64;
    float acc = 0.f;
    #pragma unroll
    for(int k4=0;k4<16;++k4){
      float4 wv4 = *(const float4*)(w + k4*4);
      acc += wv4.x*Qs[k4*4] + wv4.y*Qs[k4*4+1] + wv4.z*Qs[k4*4+2] + wv4.w*Qs[k4*4+3];
    }
    qpb[(size_t)bh*1024 + d] = f2b(acc);
  }
}

// ---------------------------------------------------------------------------
// K2: flash-fused attention pass. grid (NS=32, B=16), blk 256 (4 waves).
// Each block: 64 rows (2 chunks of 32). Writes raw s to scr[b][h][l],
// partial ctx to part[b][ns][h][d], (m,sum) to msum[b][ns][h].
__global__ __launch_bounds__(256) void k_attn(const float* __restrict__ kvsrc,
    const float* __restrict__ decrow, const unsigned short* __restrict__ qpb,
    float* __restrict__ scr, float* __restrict__ part, float* __restrict__ msum,
    int lsrc){
  int ns = blockIdx.x, b = blockIdx.y;
  int t = threadIdx.x, lane = t & 63, w = t >> 6;
  int r = lane & 15, hi = lane >> 4;
  int slice0 = ns*64;

  __shared__ unsigned short lt[32*1024];   // [l 32][d 1024] bf16, 16B-block XOR swizzle
  __shared__ float red[4*64*10];           // cross-wave score reduce
  __shared__ unsigned short p_lds[16*40];  // [h][l-in-chunk] bf16
  __shared__ float f_lds[16];              // per-h rescale factor

  // qp B-frags for this wave's d-quarter (constant across chunks)
  bf16x8 qf[8];
  {
    const unsigned short* qp = qpb + ((size_t)b*16 + r)*1024 + w*256 + hi*8;
    #pragma unroll
    for(int kk=0;kk<8;++kk) qf[kk] = *(const bf16x8*)(qp + kk*32);
  }

  f32x4 acc[16];
  #pragma unroll
  for(int i=0;i<16;++i) acc[i] = (f32x4){0.f,0.f,0.f,0.f};
  float m_run = -1e30f, s_run = 0.f;

  float4 ld[32];
  auto ISSUE = [&](int c){
    #pragma unroll
    for(int g=0; g<2; ++g){
      int row = slice0 + c*32 + g*16 + r;
      const float* rp = (row < lsrc) ? kvsrc + ((size_t)b*lsrc + row)*1024
                                     : decrow + (size_t)b*1024;
      rp += w*256 + hi*8;
      #pragma unroll
      for(int kk=0; kk<8; ++kk){
        ld[g*16+kk*2+0] = *(const float4*)(rp + kk*32);
        ld[g*16+kk*2+1] = *(const float4*)(rp + kk*32 + 4);
      }
    }
  };

  ISSUE(0);
  for(int c=0; c<2; ++c){
    __syncthreads();                       // lt free (ctx of prev chunk done)
    f32x4 s_acc0 = {0.f,0.f,0.f,0.f}, s_acc1 = {0.f,0.f,0.f,0.f};
    #pragma unroll
    for(int g=0; g<2; ++g){
      int l = g*16 + r;
      int sl = (l ^ (l>>3)) & 7;
      unsigned short* lrow = &lt[l*1024];
      #pragma unroll
      for(int kk=0; kk<8; ++kk){
        float4 a0 = ld[g*16+kk*2], a1 = ld[g*16+kk*2+1];
        bf16x8 v;
        v[0]=(short)f2b(a0.x); v[1]=(short)f2b(a0.y);
        v[2]=(short)f2b(a0.z); v[3]=(short)f2b(a0.w);
        v[4]=(short)f2b(a1.x); v[5]=(short)f2b(a1.y);
        v[6]=(short)f2b(a1.z); v[7]=(short)f2b(a1.w);
        int db = w*32 + hi + kk*4;
        *(bf16x8*)&lrow[(db ^ sl) << 3] = v;
        if(g==0) s_acc0 = mfma16(v, qf[kk], s_acc0);
        else     s_acc1 = mfma16(v, qf[kk], s_acc1);
      }
    }
    if(c == 0) ISSUE(1);                   // next chunk's loads fly during SM+PV
    *(f32x4*)&red[(w*64+lane)*10 + 0] = s_acc0;
    *(f32x4*)&red[(w*64+lane)*10 + 4] = s_acc1;
    __syncthreads();                       // red + lt visible
    if(w == 0){
      // full scores for this lane: l = g*16 + hi*4 + i, h = r
      float sf[2][4];
      #pragma unroll
      for(int g=0; g<2; ++g){
        f32x4 ss = {0.f,0.f,0.f,0.f};
        #pragma unroll
        for(int w2=0; w2<4; ++w2)
          ss += *(const f32x4*)&red[(w2*64+lane)*10 + g*4];
        sf[g][0]=ss[0]; sf[g][1]=ss[1]; sf[g][2]=ss[2]; sf[g][3]=ss[3];
      }
      float mc = -1e30f;
      #pragma unroll
      for(int g=0; g<2; ++g)
        #pragma unroll
        for(int i=0;i<4;++i) mc = fmaxf(mc, sf[g][i]);
      mc = fmaxf(mc, __shfl_xor(mc, 16));
      mc = fmaxf(mc, __shfl_xor(mc, 32));
      float nm = fmaxf(m_run, mc);
      float fch = __expf(m_run - nm);
      float ps = 0.f;
      float pv[2][4];
      #pragma unroll
      for(int g=0; g<2; ++g)
        #pragma unroll
        for(int i=0;i<4;++i){ pv[g][i] = __expf(sf[g][i] - nm); ps += pv[g][i]; }
      ps += __shfl_xor(ps, 16);
      ps += __shfl_xor(ps, 32);
      s_run = s_run*fch + ps;
      m_run = nm;
      // stage p-tile + rescale factors + raw scores
      #pragma unroll
      for(int g=0; g<2; ++g)
        #pragma unroll
        for(int i=0;i<4;++i)
          p_lds[r*40 + g*16 + hi*4 + i] = f2b(pv[g][i]);
      if(hi == 0) f_lds[r] = fch;
      float* sp = scr + ((size_t)b*16 + r)*2048 + slice0 + c*32;
      #pragma unroll
      for(int g=0; g<2; ++g)
        #pragma unroll
        for(int i=0;i<4;++i) sp[g*16 + hi*4 + i] = sf[g][i];
    }
    __syncthreads();                       // p_lds, f_lds ready
    f32x4 fv = *(const f32x4*)&f_lds[hi*4];
    bf16x8 pa = *(const bf16x8*)&p_lds[r*40 + hi*8];
    #pragma unroll
    for(int dc=0; dc<16; ++dc){
      acc[dc] *= fv;
      bf16x8 bv;
      #pragma unroll
      for(int j=0; j<8; ++j){
        int l = hi*8 + j;
        int s = (j ^ hi) & 7;
        int db = w*32 + dc*2 + (r>>3);
        bv[j] = (short)lt[l*1024 + ((db ^ s)<<3) + (r&7)];
      }
      acc[dc] = mfma16(pa, bv, acc[dc]);
    }
  }
  // epilogue: partial ctx + (m,sum)
  float* pp = part + (((size_t)b*32 + ns)*16)*1024 + w*256 + r;
  #pragma unroll
  for(int dc=0; dc<16; ++dc)
    #pragma unroll
    for(int i=0;i<4;++i)
      pp[(size_t)(hi*4+i)*1024 + dc*16] = acc[dc][i];
  if(w==0 && hi==0){
    msum[(((size_t)b*32 + ns)*16 + r)*2 + 0] = m_run;
    msum[(((size_t)b*32 + ns)*16 + r)*2 + 1] = s_run;
  }
}

// ---------------------------------------------------------------------------
// K3: combine slices + emit probs + V-projection. grid 256 (b,h), blk 256.
__global__ __launch_bounds__(256) void k_fin(const float* __restrict__ part,
    const float* __restrict__ msum, const float* __restrict__ scr,
    const float* __restrict__ wv, float* __restrict__ attn_out,
    unsigned short* __restrict__ ob){
  int bh = blockIdx.x, b = bh >> 4, h = bh & 15;
  int t = threadIdx.x;
  __shared__ float marr[32], earr[32], ctxs[1024], red2[256];
  if(t < 32){
    marr[t] = msum[(((size_t)b*32 + t)*16 + h)*2 + 0];
    earr[t] = msum[(((size_t)b*32 + t)*16 + h)*2 + 1];   // temp: sums
  }
  __syncthreads();
  float M = -1e30f;
  for(int i=0;i<32;++i) M = fmaxf(M, marr[i]);
  float SUM = 0.f;
  for(int i=0;i<32;++i) SUM += __expf(marr[i]-M)*earr[i];
  float inv = 1.f/SUM;
  __syncthreads();
  if(t < 32) earr[t] = __expf(marr[t]-M);                // slice weights
  __syncthreads();
  for(int i=0;i<4;++i){
    int d = t + i*256;
    float a = 0.f;
    for(int ns=0; ns<32; ++ns)
      a += earr[ns] * part[(((size_t)b*32 + ns)*16 + h)*1024 + d];
    ctxs[d] = a * inv;                     // R3 fix: normalize by softmax sum
  }
  const float* sp = scr + ((size_t)b*16 + h)*2048;
  float* po = attn_out + ((size_t)b*16 + h)*2048;
  for(int i=0;i<8;++i){ int l = t + i*256; po[l] = __expf(sp[l]-M)*inv; }
  __syncthreads();
  // o[b, h*64+v] = sum_d ctx[d]*wv[h,d,v]
  int v = t & 63, q = t >> 6;
  const float* wp = wv + ((size_t)h*1024 + q*256)*64 + v;
  float a0=0.f,a1=0.f,a2=0.f,a3=0.f;
  for(int dd=0; dd<256; dd+=4){
    a0 += ctxs[q*256+dd]   * wp[(size_t)dd*64];
    a1 += ctxs[q*256+dd+1] * wp[(size_t)(dd+1)*64];
    a2 += ctxs[q*256+dd+2] * wp[(size_t)(dd+2)*64];
    a3 += ctxs[q*256+dd+3] * wp[(size_t)(dd+3)*64];
  }
  red2[t] = a0+a1+a2+a3;
  __syncthreads();
  if(t < 64)
    ob[(size_t)b*1024 + h*64 + t] = f2b(red2[t]+red2[t+64]+red2[t+128]+red2[t+192]);
}

// ---------------------------------------------------------------------------
// Skinny GEMM: part[ks,b,n] = A[16,Kslice] @ W[Kslice,N]   (A bf16, W fp32->bf16)
__global__ __launch_bounds__(256) void k_skgemm(const float* __restrict__ W,
    const unsigned short* __restrict__ A, float* __restrict__ part,
    int N, int K, int KS){
  int nt = blockIdx.x, ks = blockIdx.y;
  int Ksl = K / KS, k0b = ks * Ksl, n0 = nt*64;
  int nc = Ksl >> 5;
  __shared__ unsigned short lt[2][64*40];
  int t = threadIdx.x, lane = t & 63, w = t >> 6;
  int k_loc = t >> 3, n_off = (t & 7)*8;
  const unsigned short* apb = A + (size_t)(lane & 15)*K + (lane >> 4)*8 + k0b;
  f32x4 acc = {0.f,0.f,0.f,0.f};
  float4 x0, x1;
  auto LD = [&](int c){
    const float* wp = W + (size_t)(k0b + c*32 + k_loc)*N + n0 + n_off;
    x0 = *(const float4*)wp;
    x1 = *(const float4*)(wp + 4);
  };
  auto ST = [&](int buf){
    unsigned short* p = &lt[buf][0];
    p[(n_off+0)*40 + k_loc] = f2b(x0.x);
    p[(n_off+1)*40 + k_loc] = f2b(x0.y);
    p[(n_off+2)*40 + k_loc] = f2b(x0.z);
    p[(n_off+3)*40 + k_loc] = f2b(x0.w);
    p[(n_off+4)*40 + k_loc] = f2b(x1.x);
    p[(n_off+5)*40 + k_loc] = f2b(x1.y);
    p[(n_off+6)*40 + k_loc] = f2b(x1.z);
    p[(n_off+7)*40 + k_loc] = f2b(x1.w);
  };
  LD(0); ST(0);
  for(int c=0; c<nc; ++c){
    if(c+1 < nc) LD(c+1);
    __syncthreads();
    bf16x8 af = *(const bf16x8*)(apb + c*32);
    bf16x8 bv = *(const bf16x8*)&lt[c&1][(w*16 + (lane & 15))*40 + (lane >> 4)*8];
    acc = mfma16(af, bv, acc);
    if(c+1 < nc) ST((c+1)&1);
  }
  int col = n0 + w*16 + (lane & 15);
  int r0 = (lane >> 4)*4;
  #pragma unroll
  for(int i=0;i<4;++i)
    part[ ((size_t)ks*16 + r0 + i)*(size_t)N + col ] = acc[i];
}

// LN( sum_ks parts + bias + resid ) * g + bb  -> xout (fp32) [+ bf16]  grid 16
__global__ __launch_bounds__(256) void k_lnres(const float* __restrict__ parts, int KS,
    const float* __restrict__ bias, const float* __restrict__ resid,
    const float* __restrict__ g, const float* __restrict__ bb,
    float* __restrict__ xout, unsigned short* __restrict__ xb16){
  int b = blockIdx.x, t = threadIdx.x;
  __shared__ float red[256];
  float vals[4];
  float lsum = 0.f;
  for(int i=0;i<4;++i){
    int d = t + i*256;
    float s = bias[d] + resid[(size_t)b*1024 + d];
    for(int k=0;k<KS;++k) s += parts[((size_t)k*16 + b)*1024 + d];
    vals[i] = s; lsum += s;
  }
  red[t] = lsum; __syncthreads();
  for(int off=128; off>0; off>>=1){ if(t<off) red[t]+=red[t+off]; __syncthreads(); }
  float mean = red[0]*(1.f/1024.f); __syncthreads();
  float vsum = 0.f;
  for(int i=0;i<4;++i){ float dd = vals[i]-mean; vsum += dd*dd; }
  red[t] = vsum; __syncthreads();
  for(int off=128; off>0; off>>=1){ if(t<off) red[t]+=red[t+off]; __syncthreads(); }
  float rstd = rsqrtf(red[0]*(1.f/1024.f) + 1e-5f);
  for(int i=0;i<4;++i){
    int d = t + i*256;
    float y = (vals[i]-mean)*rstd*g[d] + bb[d];
    if(xout) xout[(size_t)b*1024 + d] = y;
    if(xb16) xb16[(size_t)b*1024 + d] = f2b(y);
  }
}

// relu( sum_ks fparts + b1 ) -> h1 bf16 [16][4096]          grid 256
__global__ __launch_bounds__(256) void k_relu(const float* __restrict__ parts, int KS,
    const float* __restrict__ b1, unsigned short* __restrict__ h1){
  int i = blockIdx.x*256 + threadIdx.x;
  int f = i & 4095, b = i >> 12;
  float s = b1[f];
  for(int k=0;k<KS;++k) s += parts[((size_t)k*16 + b)*4096 + f];
  h1[i] = f2b(fmaxf(s, 0.f));
}

// ---------------------------------------------------------------------------
extern "C" void kernel_launch(void* const* d_in, const int* in_sizes, int n_in,
                              void* d_out, int out_size, void* d_ws, size_t ws_size,
                              hipStream_t stream){
  const float* dec    = (const float*)d_in[0];
  const float* hist   = (const float*)d_in[1];
  const float* enc    = (const float*)d_in[2];
  const float* wq_s   = (const float*)d_in[3];
  const float* wk_s   = (const float*)d_in[4];
  const float* wv_s   = (const float*)d_in[5];
  const float* wo_s   = (const float*)d_in[6];
  const float* bo_s   = (const float*)d_in[7];
  const float* ln1_g  = (const float*)d_in[8];
  const float* ln1_b  = (const float*)d_in[9];
  const float* wq_c   = (const float*)d_in[10];
  const float* wk_c   = (const float*)d_in[11];
  const float* wv_c   = (const float*)d_in[12];
  const float* wo_c   = (const float*)d_in[13];
  const float* bo_c   = (const float*)d_in[14];
  const float* ln2_g  = (const float*)d_in[15];
  const float* ln2_b  = (const float*)d_in[16];
  const float* ffn_w1 = (const float*)d_in[17];
  const float* ffn_b1 = (const float*)d_in[18];
  const float* ffn_w2 = (const float*)d_in[19];
  const float* ffn_b2 = (const float*)d_in[20];
  const float* ln3_g  = (const float*)d_in[21];
  const float* ln3_b  = (const float*)d_in[22];

  float* out      = (float*)d_out;              // [16][1024]
  float* slf_out  = out + 16384;                // [16][16][2048]
  float* enc_out  = out + 16384 + 524288;       // [16][16][2048]

  char* w = (char*)d_ws;
  float*          scr   = (float*)(w + 0x0000000);           // 2 MB  [16][16][2048]
  float*          part  = (float*)(w + 0x0200000);           // 32 MB [16][32][16][1024]
  float*          msum  = (float*)(w + 0x2200000);           // 64K   [16][32][16][2]
  unsigned short* qpb   = (unsigned short*)(w + 0x2210000);  // 512K  [16][16][1024]
  unsigned short* ob    = (unsigned short*)(w + 0x2290000);  // 32K   [16][1024]
  float*          x1    = (float*)(w + 0x22A0000);           // 64K
  float*          x2    = (float*)(w + 0x22B0000);           // 64K
  unsigned short* x2b   = (unsigned short*)(w + 0x22C0000);  // 32K
  unsigned short* h1b   = (unsigned short*)(w + 0x22D0000);  // 128K  [16][4096]
  float*          gpart = (float*)(w + 0x2300000);           // 1 MB  [16][16][1024]
  float*          fpart = (float*)(w + 0x2400000);           // 2 MB  [8][16][4096]
  float*          g2part= (float*)(w + 0x2600000);           // 2 MB  [32][16][1024]

  // ---- self attention ----
  k_qp2   <<<256, 256, 0, stream>>>(dec, wq_s, wk_s, qpb);
  k_attn  <<<dim3(32,16), 256, 0, stream>>>(hist, dec, qpb, scr, part, msum, 2047);
  k_fin   <<<256, 256, 0, stream>>>(part, msum, scr, wv_s, slf_out, ob);
  k_skgemm<<<dim3(16,16), 256, 0, stream>>>(wo_s, ob, gpart, 1024, 1024, 16);
  k_lnres <<<16, 256, 0, stream>>>(gpart, 16, bo_s, dec, ln1_g, ln1_b, x1, (unsigned short*)nullptr);

  // ---- cross attention ----
  k_qp2   <<<256, 256, 0, stream>>>(x1, wq_c, wk_c, qpb);
  k_attn  <<<dim3(32,16), 256, 0, stream>>>(enc, dec, qpb, scr, part, msum, 2048);
  k_fin   <<<256, 256, 0, stream>>>(part, msum, scr, wv_c, enc_out, ob);
  k_skgemm<<<dim3(16,16), 256, 0, stream>>>(wo_c, ob, gpart, 1024, 1024, 16);
  k_lnres <<<16, 256, 0, stream>>>(gpart, 16, bo_c, x1, ln2_g, ln2_b, x2, x2b);

  // ---- FFN + final LN ----
  k_skgemm<<<dim3(64,8), 256, 0, stream>>>(ffn_w1, x2b, fpart, 4096, 1024, 8);
  k_relu  <<<256, 256, 0, stream>>>(fpart, 8, ffn_b1, h1b);
  k_skgemm<<<dim3(16,32), 256, 0, stream>>>(ffn_w2, h1b, g2part, 1024, 4096, 32);
  k_lnres <<<16, 256, 0, stream>>>(g2part, 32, ffn_b2, x2, ln3_g, ln3_b, out, (unsigned short*)nullptr);
}

// Round 5
// 197.341 us; speedup vs baseline: 1.5974x; 1.3598x over previous
//
#include <hip/hip_runtime.h>
#include <hip/hip_bf16.h>
#include <stdint.h>
#include <stddef.h>

// DecoderStepLayer: B=16, Lq=1, L=2048 (self: 2047 hist + dec row; cross: enc 2048),
// D=1024, H=16, DK=DV=64, DF=4096.
// R4: k_attn rebuilt: chunk=16 rows (ld[16] staging, ~190 VGPR, no spill risk),
// LDS tile stored TRANSPOSED ([d][l], pitch 24, XOR l-block swizzle) so the PV
// B-fragment is one aligned ds_read_b128 (was 128 scalar u16 reads/chunk).
// All-wave redundant softmax (no wave0-only divergence). Small kernels float4.

#define DEV __device__ __forceinline__

typedef __attribute__((ext_vector_type(8))) short bf16x8;
typedef __attribute__((ext_vector_type(4))) float f32x4;

DEV unsigned short f2b(float f){
  union { __hip_bfloat16 h; unsigned short u; } cv;
  cv.h = __float2bfloat16(f);
  return cv.u;
}
DEV f32x4 mfma16(bf16x8 a, bf16x8 b, f32x4 c){
  return __builtin_amdgcn_mfma_f32_16x16x32_bf16(a, b, c, 0, 0, 0);
}
DEV float4 fma4(float4 a, float s, float4 b){
  a.x += s*b.x; a.y += s*b.y; a.z += s*b.z; a.w += s*b.w; return a;
}

// ---------------------------------------------------------------------------
// K1: qpb[b,h,d] = bf16( sum_k wk[h,d,k] * (0.125 * sum_d' src[b,d']*wq[h,d',k]) )
__global__ __launch_bounds__(256) void k_qp2(const float* __restrict__ src,
    const float* __restrict__ wq, const float* __restrict__ wk,
    unsigned short* __restrict__ qpb){
  int bh = blockIdx.x, b = bh >> 4, h = bh & 15;
  int t = threadIdx.x;
  __shared__ float red[256];
  __shared__ float Qs[64];
  {
    int k = t & 63, q = t >> 6;
    const float* s = src + (size_t)b*1024 + q*256;
    const float* w = wq + (size_t)h*65536 + (size_t)(q*256)*64 + k;
    float a0=0.f,a1=0.f,a2=0.f,a3=0.f;
    for(int d=0; d<256; d+=4){
      a0 += s[d]   * w[(size_t)d*64];
      a1 += s[d+1] * w[(size_t)(d+1)*64];
      a2 += s[d+2] * w[(size_t)(d+2)*64];
      a3 += s[d+3] * w[(size_t)(d+3)*64];
    }
    red[t] = a0+a1+a2+a3;
    __syncthreads();
    if(t < 64) Qs[t] = (red[t]+red[t+64]+red[t+128]+red[t+192])*0.125f;
    __syncthreads();
  }
  for(int i=0;i<4;++i){
    int d = t + i*256;
    const float* w = wk + ((size_t)h*1024 + d)*64;
    float acc = 0.f;
    #pragma unroll
    for(int k4=0;k4<16;++k4){
      float4 wv4 = *(const float4*)(w + k4*4);
      acc += wv4.x*Qs[k4*4] + wv4.y*Qs[k4*4+1] + wv4.z*Qs[k4*4+2] + wv4.w*Qs[k4*4+3];
    }
    qpb[(size_t)bh*1024 + d] = f2b(acc);
  }
}

// ---------------------------------------------------------------------------
// K2: flash-fused attention pass. grid (NS=32, B=16), blk 256 (4 waves).
// Block = 64 rows (4 chunks of 16). Each wave owns d-quarter w*256..+255.
// lt transposed: lt[d][l], pitch 24 u16, col = l ^ (((d>>3)&1)<<3).
__global__ __launch_bounds__(256) void k_attn(const float* __restrict__ kvsrc,
    const float* __restrict__ decrow, const unsigned short* __restrict__ qpb,
    float* __restrict__ scr, float* __restrict__ part, float* __restrict__ msum,
    int lsrc){
  int ns = blockIdx.x, b = blockIdx.y;
  int t = threadIdx.x, lane = t & 63, w = t >> 6;
  int r = lane & 15, hi = lane >> 4;
  int slice0 = ns*64;

  __shared__ unsigned short lt[1024*24];   // 48 KB transposed KV tile
  __shared__ float red[4*64*4];            // 4 KB cross-wave score reduce
  __shared__ unsigned short p_lds[16*40];  // [h][l 0..31], cols 16..31 stay 0
  __shared__ float f_lds[16];              // per-h rescale factor

  float4 ld[16];
  auto ISSUE = [&](int c){
    int row = slice0 + c*16 + r;
    const float* rp = (row < lsrc) ? kvsrc + ((size_t)b*lsrc + row)*1024
                                   : decrow + (size_t)b*1024;
    rp += w*256 + hi*8;
    #pragma unroll
    for(int kk=0; kk<8; ++kk){
      ld[kk*2+0] = *(const float4*)(rp + kk*32);
      ld[kk*2+1] = *(const float4*)(rp + kk*32 + 4);
    }
  };

  ISSUE(0);
  for(int i=t; i<16*40; i+=256) p_lds[i] = 0;

  bf16x8 qf[8];
  {
    const unsigned short* qp = qpb + ((size_t)b*16 + r)*1024 + w*256 + hi*8;
    #pragma unroll
    for(int kk=0;kk<8;++kk) qf[kk] = *(const bf16x8*)(qp + kk*32);
  }

  f32x4 acc[16];
  #pragma unroll
  for(int i=0;i<16;++i) acc[i] = (f32x4){0.f,0.f,0.f,0.f};
  float m_run = -1e30f, s_run = 0.f;

  __syncthreads();                         // p_lds zeros visible
  for(int c=0; c<4; ++c){
    // ---- scores + transposed LDS deposit ----
    f32x4 s_acc = {0.f,0.f,0.f,0.f};
    int colw = r ^ ((hi & 1) << 3);
    #pragma unroll
    for(int kk=0; kk<8; ++kk){
      float4 a0 = ld[kk*2], a1 = ld[kk*2+1];
      bf16x8 v;
      v[0]=(short)f2b(a0.x); v[1]=(short)f2b(a0.y);
      v[2]=(short)f2b(a0.z); v[3]=(short)f2b(a0.w);
      v[4]=(short)f2b(a1.x); v[5]=(short)f2b(a1.y);
      v[6]=(short)f2b(a1.z); v[7]=(short)f2b(a1.w);
      unsigned short* pt = &lt[(w*256 + hi*8 + kk*32)*24 + colw];
      #pragma unroll
      for(int j=0;j<8;++j) pt[j*24] = (unsigned short)v[j];
      s_acc = mfma16(v, qf[kk], s_acc);
    }
    if(c < 3) ISSUE(c+1);                  // next chunk's loads fly through SM+PV
    *(f32x4*)&red[t*4] = s_acc;
    __syncthreads();                       // (A) red + lt visible

    // ---- all-wave redundant online softmax (h = r, l = hi*4+i) ----
    f32x4 ss = *(const f32x4*)&red[(0*64+lane)*4];
    ss += *(const f32x4*)&red[(1*64+lane)*4];
    ss += *(const f32x4*)&red[(2*64+lane)*4];
    ss += *(const f32x4*)&red[(3*64+lane)*4];
    float sf[4] = {ss[0], ss[1], ss[2], ss[3]};
    float mc = fmaxf(fmaxf(sf[0],sf[1]), fmaxf(sf[2],sf[3]));
    mc = fmaxf(mc, __shfl_xor(mc, 16));
    mc = fmaxf(mc, __shfl_xor(mc, 32));
    float nm = fmaxf(m_run, mc);
    float fch = __expf(m_run - nm);
    float pvv[4]; float ps = 0.f;
    #pragma unroll
    for(int i=0;i<4;++i){ pvv[i] = __expf(sf[i]-nm); ps += pvv[i]; }
    ps += __shfl_xor(ps, 16);
    ps += __shfl_xor(ps, 32);
    s_run = s_run*fch + ps;
    m_run = nm;
    if(w == 0){
      #pragma unroll
      for(int i=0;i<4;++i) p_lds[r*40 + hi*4 + i] = f2b(pvv[i]);
      if(hi == 0) f_lds[r] = fch;
      float* sp = scr + ((size_t)b*16 + r)*2048 + slice0 + c*16 + hi*4;
      *(float4*)sp = (float4){sf[0], sf[1], sf[2], sf[3]};
    }
    __syncthreads();                       // (B) p_lds, f_lds ready

    // ---- PV: acc[h][d] rescale + P x V ----
    f32x4 fv = *(const f32x4*)&f_lds[hi*4];
    bf16x8 pa = *(const bf16x8*)&p_lds[r*40 + hi*8];
    #pragma unroll
    for(int dc=0; dc<16; ++dc){
      acc[dc] *= fv;
      int d = w*256 + dc*16 + r;
      int col0 = (((hi & 1) ^ ((r >> 3) & 1)) << 3);
      bf16x8 bv = *(const bf16x8*)&lt[d*24 + col0];
      acc[dc] = mfma16(pa, bv, acc[dc]);
    }
    __syncthreads();                       // (C) PV reads done before next deposit
  }
  // epilogue: partial ctx + (m,sum)
  float* pp = part + (((size_t)b*32 + ns)*16)*1024 + w*256 + r;
  #pragma unroll
  for(int dc=0; dc<16; ++dc)
    #pragma unroll
    for(int i=0;i<4;++i)
      pp[(size_t)(hi*4+i)*1024 + dc*16] = acc[dc][i];
  if(w==0 && hi==0){
    msum[(((size_t)b*32 + ns)*16 + r)*2 + 0] = m_run;
    msum[(((size_t)b*32 + ns)*16 + r)*2 + 1] = s_run;
  }
}

// ---------------------------------------------------------------------------
// K3: combine slices + emit probs + V-projection. grid 256 (b,h), blk 256.
__global__ __launch_bounds__(256) void k_fin(const float* __restrict__ part,
    const float* __restrict__ msum, const float* __restrict__ scr,
    const float* __restrict__ wv, float* __restrict__ attn_out,
    unsigned short* __restrict__ ob){
  int bh = blockIdx.x, b = bh >> 4, h = bh & 15;
  int t = threadIdx.x;
  __shared__ float marr[32], earr[32], ctxs[1024], red2[256];
  if(t < 32){
    marr[t] = msum[(((size_t)b*32 + t)*16 + h)*2 + 0];
    earr[t] = msum[(((size_t)b*32 + t)*16 + h)*2 + 1];   // temp: slice sums
  }
  __syncthreads();
  float M = -1e30f;
  for(int i=0;i<32;++i) M = fmaxf(M, marr[i]);
  float SUM = 0.f;
  for(int i=0;i<32;++i) SUM += __expf(marr[i]-M)*earr[i];
  float inv = 1.f/SUM;
  __syncthreads();
  if(t < 32) earr[t] = __expf(marr[t]-M)*inv;            // normalized slice weights
  __syncthreads();
  {
    const float4* p4 = (const float4*)part + ((size_t)b*32*16 + h)*256 + t;
    float4 a = {0.f,0.f,0.f,0.f};
    #pragma unroll 4
    for(int nsq=0; nsq<32; ++nsq) a = fma4(a, earr[nsq], p4[(size_t)nsq*4096]);
    *(float4*)&ctxs[t*4] = a;
  }
  const float* sp = scr + ((size_t)b*16 + h)*2048;
  float* po = attn_out + ((size_t)b*16 + h)*2048;
  #pragma unroll
  for(int i=0;i<8;++i){ int l = t + i*256; po[l] = __expf(sp[l]-M)*inv; }
  __syncthreads();
  // o[b, h*64+v] = sum_d ctx[d]*wv[h,d,v]
  int v = t & 63, q = t >> 6;
  const float* wp = wv + ((size_t)h*1024 + q*256)*64 + v;
  float a0=0.f,a1=0.f,a2=0.f,a3=0.f;
  for(int dd=0; dd<256; dd+=4){
    a0 += ctxs[q*256+dd]   * wp[(size_t)dd*64];
    a1 += ctxs[q*256+dd+1] * wp[(size_t)(dd+1)*64];
    a2 += ctxs[q*256+dd+2] * wp[(size_t)(dd+2)*64];
    a3 += ctxs[q*256+dd+3] * wp[(size_t)(dd+3)*64];
  }
  red2[t] = a0+a1+a2+a3;
  __syncthreads();
  if(t < 64)
    ob[(size_t)b*1024 + h*64 + t] = f2b(red2[t]+red2[t+64]+red2[t+128]+red2[t+192]);
}

// ---------------------------------------------------------------------------
// Skinny GEMM: part[ks,b,n] = A[16,Kslice] @ W[Kslice,N]   (A bf16, W fp32->bf16)
__global__ __launch_bounds__(256) void k_skgemm(const float* __restrict__ W,
    const unsigned short* __restrict__ A, float* __restrict__ part,
    int N, int K, int KS){
  int nt = blockIdx.x, ks = blockIdx.y;
  int Ksl = K / KS, k0b = ks * Ksl, n0 = nt*64;
  int nc = Ksl >> 5;
  __shared__ unsigned short lt[2][64*40];
  int t = threadIdx.x, lane = t & 63, w = t >> 6;
  int k_loc = t >> 3, n_off = (t & 7)*8;
  const unsigned short* apb = A + (size_t)(lane & 15)*K + (lane >> 4)*8 + k0b;
  f32x4 acc = {0.f,0.f,0.f,0.f};
  float4 x0, x1;
  auto LD = [&](int c){
    const float* wp = W + (size_t)(k0b + c*32 + k_loc)*N + n0 + n_off;
    x0 = *(const float4*)wp;
    x1 = *(const float4*)(wp + 4);
  };
  auto ST = [&](int buf){
    unsigned short* p = &lt[buf][0];
    p[(n_off+0)*40 + k_loc] = f2b(x0.x);
    p[(n_off+1)*40 + k_loc] = f2b(x0.y);
    p[(n_off+2)*40 + k_loc] = f2b(x0.z);
    p[(n_off+3)*40 + k_loc] = f2b(x0.w);
    p[(n_off+4)*40 + k_loc] = f2b(x1.x);
    p[(n_off+5)*40 + k_loc] = f2b(x1.y);
    p[(n_off+6)*40 + k_loc] = f2b(x1.z);
    p[(n_off+7)*40 + k_loc] = f2b(x1.w);
  };
  LD(0); ST(0);
  for(int c=0; c<nc; ++c){
    if(c+1 < nc) LD(c+1);
    __syncthreads();
    bf16x8 af = *(const bf16x8*)(apb + c*32);
    bf16x8 bv = *(const bf16x8*)&lt[c&1][(w*16 + (lane & 15))*40 + (lane >> 4)*8];
    acc = mfma16(af, bv, acc);
    if(c+1 < nc) ST((c+1)&1);
  }
  int col = n0 + w*16 + (lane & 15);
  int r0 = (lane >> 4)*4;
  #pragma unroll
  for(int i=0;i<4;++i)
    part[ ((size_t)ks*16 + r0 + i)*(size_t)N + col ] = acc[i];
}

// LN( sum_ks parts + bias + resid ) * g + bb  -> xout (fp32) [+ bf16]  grid 16
__global__ __launch_bounds__(256) void k_lnres(const float* __restrict__ parts, int KS,
    const float* __restrict__ bias, const float* __restrict__ resid,
    const float* __restrict__ g, const float* __restrict__ bb,
    float* __restrict__ xout, unsigned short* __restrict__ xb16){
  int b = blockIdx.x, t = threadIdx.x;
  __shared__ float red[256];
  const float4* bias4  = (const float4*)bias;
  const float4* resid4 = (const float4*)resid + (size_t)b*256;
  const float4* parts4 = (const float4*)parts;
  float4 s = bias4[t];
  { float4 rr = resid4[t]; s.x+=rr.x; s.y+=rr.y; s.z+=rr.z; s.w+=rr.w; }
  #pragma unroll 4
  for(int k=0;k<KS;++k){
    float4 pp = parts4[((size_t)k*16 + b)*256 + t];
    s.x+=pp.x; s.y+=pp.y; s.z+=pp.z; s.w+=pp.w;
  }
  red[t] = s.x+s.y+s.z+s.w; __syncthreads();
  for(int off=128; off>0; off>>=1){ if(t<off) red[t]+=red[t+off]; __syncthreads(); }
  float mean = red[0]*(1.f/1024.f); __syncthreads();
  float dx=s.x-mean, dy=s.y-mean, dz=s.z-mean, dw=s.w-mean;
  red[t] = dx*dx+dy*dy+dz*dz+dw*dw; __syncthreads();
  for(int off=128; off>0; off>>=1){ if(t<off) red[t]+=red[t+off]; __syncthreads(); }
  float rstd = rsqrtf(red[0]*(1.f/1024.f) + 1e-5f);
  float4 g4 = ((const float4*)g)[t], b4 = ((const float4*)bb)[t];
  float4 y;
  y.x = dx*rstd*g4.x + b4.x;
  y.y = dy*rstd*g4.y + b4.y;
  y.z = dz*rstd*g4.z + b4.z;
  y.w = dw*rstd*g4.w + b4.w;
  if(xout) ((float4*)xout)[(size_t)b*256 + t] = y;
  if(xb16){
    ushort4 u;
    u.x = f2b(y.x); u.y = f2b(y.y); u.z = f2b(y.z); u.w = f2b(y.w);
    ((ushort4*)xb16)[(size_t)b*256 + t] = u;
  }
}

// relu( sum_ks fparts + b1 ) -> h1 bf16 [16][4096]          grid 64
__global__ __launch_bounds__(256) void k_relu(const float* __restrict__ parts, int KS,
    const float* __restrict__ b1, unsigned short* __restrict__ h1){
  int i = blockIdx.x*256 + threadIdx.x;   // float4 index over 16*1024
  int b = i >> 10, f4 = i & 1023;
  float4 s = ((const float4*)b1)[f4];
  #pragma unroll 4
  for(int k=0;k<KS;++k){
    float4 pp = ((const float4*)parts)[((size_t)k*16 + b)*1024 + f4];
    s.x+=pp.x; s.y+=pp.y; s.z+=pp.z; s.w+=pp.w;
  }
  ushort4 u;
  u.x = f2b(fmaxf(s.x,0.f)); u.y = f2b(fmaxf(s.y,0.f));
  u.z = f2b(fmaxf(s.z,0.f)); u.w = f2b(fmaxf(s.w,0.f));
  ((ushort4*)h1)[i] = u;
}

// ---------------------------------------------------------------------------
extern "C" void kernel_launch(void* const* d_in, const int* in_sizes, int n_in,
                              void* d_out, int out_size, void* d_ws, size_t ws_size,
                              hipStream_t stream){
  const float* dec    = (const float*)d_in[0];
  const float* hist   = (const float*)d_in[1];
  const float* enc    = (const float*)d_in[2];
  const float* wq_s   = (const float*)d_in[3];
  const float* wk_s   = (const float*)d_in[4];
  const float* wv_s   = (const float*)d_in[5];
  const float* wo_s   = (const float*)d_in[6];
  const float* bo_s   = (const float*)d_in[7];
  const float* ln1_g  = (const float*)d_in[8];
  const float* ln1_b  = (const float*)d_in[9];
  const float* wq_c   = (const float*)d_in[10];
  const float* wk_c   = (const float*)d_in[11];
  const float* wv_c   = (const float*)d_in[12];
  const float* wo_c   = (const float*)d_in[13];
  const float* bo_c   = (const float*)d_in[14];
  const float* ln2_g  = (const float*)d_in[15];
  const float* ln2_b  = (const float*)d_in[16];
  const float* ffn_w1 = (const float*)d_in[17];
  const float* ffn_b1 = (const float*)d_in[18];
  const float* ffn_w2 = (const float*)d_in[19];
  const float* ffn_b2 = (const float*)d_in[20];
  const float* ln3_g  = (const float*)d_in[21];
  const float* ln3_b  = (const float*)d_in[22];

  float* out      = (float*)d_out;              // [16][1024]
  float* slf_out  = out + 16384;                // [16][16][2048]
  float* enc_out  = out + 16384 + 524288;       // [16][16][2048]

  char* w = (char*)d_ws;
  float*          scr   = (float*)(w + 0x0000000);           // 2 MB  [16][16][2048]
  float*          part  = (float*)(w + 0x0200000);           // 32 MB [16][32][16][1024]
  float*          msum  = (float*)(w + 0x2200000);           // 64K   [16][32][16][2]
  unsigned short* qpb   = (unsigned short*)(w + 0x2210000);  // 512K  [16][16][1024]
  unsigned short* ob    = (unsigned short*)(w + 0x2290000);  // 32K   [16][1024]
  float*          x1    = (float*)(w + 0x22A0000);           // 64K
  float*          x2    = (float*)(w + 0x22B0000);           // 64K
  unsigned short* x2b   = (unsigned short*)(w + 0x22C0000);  // 32K
  unsigned short* h1b   = (unsigned short*)(w + 0x22D0000);  // 128K  [16][4096]
  float*          gpart = (float*)(w + 0x2300000);           // 1 MB  [16][16][1024]
  float*          fpart = (float*)(w + 0x2400000);           // 2 MB  [8][16][4096]
  float*          g2part= (float*)(w + 0x2600000);           // 2 MB  [32][16][1024]

  // ---- self attention ----
  k_qp2   <<<256, 256, 0, stream>>>(dec, wq_s, wk_s, qpb);
  k_attn  <<<dim3(32,16), 256, 0, stream>>>(hist, dec, qpb, scr, part, msum, 2047);
  k_fin   <<<256, 256, 0, stream>>>(part, msum, scr, wv_s, slf_out, ob);
  k_skgemm<<<dim3(16,16), 256, 0, stream>>>(wo_s, ob, gpart, 1024, 1024, 16);
  k_lnres <<<16, 256, 0, stream>>>(gpart, 16, bo_s, dec, ln1_g, ln1_b, x1, (unsigned short*)nullptr);

  // ---- cross attention ----
  k_qp2   <<<256, 256, 0, stream>>>(x1, wq_c, wk_c, qpb);
  k_attn  <<<dim3(32,16), 256, 0, stream>>>(enc, dec, qpb, scr, part, msum, 2048);
  k_fin   <<<256, 256, 0, stream>>>(part, msum, scr, wv_c, enc_out, ob);
  k_skgemm<<<dim3(16,16), 256, 0, stream>>>(wo_c, ob, gpart, 1024, 1024, 16);
  k_lnres <<<16, 256, 0, stream>>>(gpart, 16, bo_c, x1, ln2_g, ln2_b, x2, x2b);

  // ---- FFN + final LN ----
  k_skgemm<<<dim3(64,8), 256, 0, stream>>>(ffn_w1, x2b, fpart, 4096, 1024, 8);
  k_relu  <<<64, 256, 0, stream>>>(fpart, 8, ffn_b1, h1b);
  k_skgemm<<<dim3(16,32), 256, 0, stream>>>(ffn_w2, h1b, g2part, 1024, 4096, 32);
  k_lnres <<<16, 256, 0, stream>>>(g2part, 32, ffn_b2, x2, ln3_g, ln3_b, out, (unsigned short*)nullptr);
}